// Round 12
// baseline (2134.607 us; speedup 1.0000x reference)
//
#include <hip/hip_runtime.h>
#include <hip/hip_bf16.h>

#define D 64
#define BSZ 512               // nodes per dst-bucket (window ~ 512*12*128B ~ 786KB)

typedef unsigned short u16;
typedef unsigned long long u64;
typedef __attribute__((ext_vector_type(8))) unsigned short u16x8;

static __device__ __forceinline__ u16 f2bf(float f) {
    unsigned u = __float_as_uint(f);
    unsigned r = (u + 0x7FFFu + ((u >> 16) & 1u)) >> 16;   // RNE
    return (u16)r;
}
static __device__ __forceinline__ float bf2f(u16 h) {
    return __uint_as_float(((unsigned)h) << 16);
}

// ---------------------------------------------------------------------------
__global__ void out_init_kernel(float* __restrict__ out, const float* __restrict__ bout, int G) {
    int i = blockIdx.x * blockDim.x + threadIdx.x;
    if (i < G) out[i] = bout[0];
}

// ---------------------------------------------------------------------------
// CSR build: histogram -> scan -> bucket bases
// ---------------------------------------------------------------------------
__global__ void deg_hist_kernel(const int* __restrict__ ei, int* __restrict__ deg, int E) {
    int e = blockIdx.x * blockDim.x + threadIdx.x;
    if (e < E) atomicAdd(&deg[ei[E + e]], 1);
}

__global__ __launch_bounds__(1024) void scan1_kernel(
    const int* __restrict__ deg, int* __restrict__ off, int* __restrict__ bsum, int N)
{
    __shared__ int sh[1024];
    int t = threadIdx.x;
    int i = blockIdx.x * 1024 + t;
    int v = (i < N) ? deg[i] : 0;
    sh[t] = v;
    __syncthreads();
#pragma unroll
    for (int o = 1; o < 1024; o <<= 1) {
        int u = (t >= o) ? sh[t - o] : 0;
        __syncthreads();
        sh[t] += u;
        __syncthreads();
    }
    if (i < N) off[i] = sh[t] - v;
    if (t == 1023) bsum[blockIdx.x] = sh[t];
}

__global__ __launch_bounds__(128) void scan2_kernel(
    const int* __restrict__ bsum, int* __restrict__ boff, int nb)
{
    __shared__ int sh[128];
    int t = threadIdx.x;
    int v = (t < nb) ? bsum[t] : 0;
    sh[t] = v;
    __syncthreads();
#pragma unroll
    for (int o = 1; o < 128; o <<= 1) {
        int u = (t >= o) ? sh[t - o] : 0;
        __syncthreads();
        sh[t] += u;
        __syncthreads();
    }
    if (t < nb) boff[t] = sh[t] - v;
}

__global__ void scan3_kernel(int* __restrict__ off, const int* __restrict__ boff, int N) {
    int i = blockIdx.x * blockDim.x + threadIdx.x;
    if (i < N) off[i] += boff[i >> 10];
}

__global__ void bucket_base_kernel(const int* __restrict__ off, int* __restrict__ bbase, int N, int NB) {
    int b = blockIdx.x * blockDim.x + threadIdx.x;
    if (b < NB) bbase[b] = off[b * BSZ];
}

// ---------------------------------------------------------------------------
// build2: single pass.  Wave handles 4 edges, 16 lanes/edge.
// Sequential fp32 ea read -> bf16 row appended to the dst bucket's region
// (196 quasi-sequential write streams).  pos[p]=q gives slot->staged location;
// src_csr[p] scattered 4B (small).
// ---------------------------------------------------------------------------
__global__ __launch_bounds__(256) void build2_kernel(
    const float* __restrict__ ea, const int* __restrict__ ei,
    const int* __restrict__ off, int* __restrict__ cur,
    const int* __restrict__ bbase, int* __restrict__ bcur,
    int* __restrict__ src_csr, int* __restrict__ pos,
    u16* __restrict__ stage, int E)
{
    const int lane = threadIdx.x & 63;
    const int q = lane & 15, g = lane >> 4;
    const long long wv = (long long)blockIdx.x * 4 + (threadIdx.x >> 6);
    const int e = (int)(wv * 4) + g;

    int qs = 0;
    if (e < E && q == 0) {
        int d = ei[E + e];
        int s = ei[e];
        int b = d / BSZ;
        qs = bbase[b] + atomicAdd(&bcur[b], 1);          // staged location
        int p  = off[d] + atomicAdd(&cur[d], 1);         // CSR slot
        src_csr[p] = s;
        pos[p]     = qs;
    }
    qs = __shfl(qs, lane & 48, 64);      // broadcast staged location
    if (e >= E) return;

    float4 v = *(const float4*)&ea[(size_t)e * D + q * 4];
    u64 pk = (u64)f2bf(v.x) | ((u64)f2bf(v.y) << 16)
           | ((u64)f2bf(v.z) << 32) | ((u64)f2bf(v.w) << 48);
    *(u64*)&stage[(size_t)qs * D + q * 4] = pk;
    if (false) (void)0;
}

// ---------------------------------------------------------------------------
// convx: fp32 node features -> bf16 (identity order, fully sequential)
// ---------------------------------------------------------------------------
__global__ __launch_bounds__(256) void convx_kernel(
    const float* __restrict__ xf, u16* __restrict__ xb, long long n4)
{
    long long i = (long long)blockIdx.x * blockDim.x + threadIdx.x;
    if (i >= n4) return;
    float4 v = ((const float4*)xf)[i];
    ushort4 o;
    o.x = f2bf(v.x); o.y = f2bf(v.y); o.z = f2bf(v.z); o.w = f2bf(v.w);
    ((ushort4*)xb)[i] = o;
}

// ---------------------------------------------------------------------------
// aggregate: wave per node, 8 lanes/edge, 8 edges per chunk, 2-deep pipeline.
// Edge rows fetched at stage[pos[p]] — random only within the node's bucket
// window (~786KB, L2-resident; windows advance with node order -> quasi-seq
// at HBM granularity).  src/pos preloaded coalesced, shfl-distributed.
// ---------------------------------------------------------------------------
__global__ __launch_bounds__(256) void aggregate_kernel(
    const u16* __restrict__ xbf, const u16* __restrict__ stage,
    const int* __restrict__ src_csr, const int* __restrict__ pos,
    const int* __restrict__ off, const int* __restrict__ deg,
    float* __restrict__ h, int N)
{
    const int lane = threadIdx.x & 63;
    const int sub  = lane & 7;        // dim octet
    const int g    = lane >> 3;       // edge slot 0..7
    const int n = (blockIdx.x << 2) + (threadIdx.x >> 6);
    if (n >= N) return;

    const int p0 = off[n];
    const int dg = deg[n];

    u16x8 xs;                          // self row (consumed at the end)
    if (g == 0) xs = *(const u16x8*)&xbf[(size_t)n * D + sub * 8];

    float a0=0.f,a1=0.f,a2=0.f,a3=0.f,a4=0.f,a5=0.f,a6=0.f,a7=0.f;

    if (dg > 0) {
        const int pre    = p0 + min(lane, dg - 1);
        const int srcAll = src_csr[pre];
        const int posAll = pos[pre];
        const int nct = (dg + 7) >> 3;

        // ---- issue chunk 0 ----
        int e0 = min(g, dg - 1);
        int s0 = __shfl(srcAll, e0, 64);
        int q0 = __shfl(posAll, e0, 64);
        u16x8 evA = *(const u16x8*)&stage[(size_t)q0 * D + sub * 8];
        u16x8 xvA = *(const u16x8*)&xbf[(size_t)s0 * D + sub * 8];
        float mA = (g < dg) ? 1.f : 0.f;

        for (int c = 1; c < nct; ++c) {
            // ---- issue chunk c ----
            int e1 = min(c * 8 + g, dg - 1);
            int sv = __shfl(srcAll, e1 & 63, 64);
            int qv = __shfl(posAll, e1 & 63, 64);
            int s1 = (e1 < 64) ? sv : src_csr[p0 + e1];
            int q1 = (e1 < 64) ? qv : pos[p0 + e1];
            u16x8 evB = *(const u16x8*)&stage[(size_t)q1 * D + sub * 8];
            u16x8 xvB = *(const u16x8*)&xbf[(size_t)s1 * D + sub * 8];
            float mB = (c * 8 + g < dg) ? 1.f : 0.f;

            // ---- consume chunk c-1 ----
            a0 = fmaf(mA, fmaxf(bf2f(xvA[0]) + bf2f(evA[0]), 0.f), a0);
            a1 = fmaf(mA, fmaxf(bf2f(xvA[1]) + bf2f(evA[1]), 0.f), a1);
            a2 = fmaf(mA, fmaxf(bf2f(xvA[2]) + bf2f(evA[2]), 0.f), a2);
            a3 = fmaf(mA, fmaxf(bf2f(xvA[3]) + bf2f(evA[3]), 0.f), a3);
            a4 = fmaf(mA, fmaxf(bf2f(xvA[4]) + bf2f(evA[4]), 0.f), a4);
            a5 = fmaf(mA, fmaxf(bf2f(xvA[5]) + bf2f(evA[5]), 0.f), a5);
            a6 = fmaf(mA, fmaxf(bf2f(xvA[6]) + bf2f(evA[6]), 0.f), a6);
            a7 = fmaf(mA, fmaxf(bf2f(xvA[7]) + bf2f(evA[7]), 0.f), a7);

            xvA = xvB; evA = evB; mA = mB;
        }
        // ---- consume last chunk ----
        a0 = fmaf(mA, fmaxf(bf2f(xvA[0]) + bf2f(evA[0]), 0.f), a0);
        a1 = fmaf(mA, fmaxf(bf2f(xvA[1]) + bf2f(evA[1]), 0.f), a1);
        a2 = fmaf(mA, fmaxf(bf2f(xvA[2]) + bf2f(evA[2]), 0.f), a2);
        a3 = fmaf(mA, fmaxf(bf2f(xvA[3]) + bf2f(evA[3]), 0.f), a3);
        a4 = fmaf(mA, fmaxf(bf2f(xvA[4]) + bf2f(evA[4]), 0.f), a4);
        a5 = fmaf(mA, fmaxf(bf2f(xvA[5]) + bf2f(evA[5]), 0.f), a5);
        a6 = fmaf(mA, fmaxf(bf2f(xvA[6]) + bf2f(evA[6]), 0.f), a6);
        a7 = fmaf(mA, fmaxf(bf2f(xvA[7]) + bf2f(evA[7]), 0.f), a7);
    }

    // reduce across the 8 edge-groups
#pragma unroll
    for (int o = 8; o < 64; o <<= 1) {
        a0 += __shfl_xor(a0, o, 64);  a1 += __shfl_xor(a1, o, 64);
        a2 += __shfl_xor(a2, o, 64);  a3 += __shfl_xor(a3, o, 64);
        a4 += __shfl_xor(a4, o, 64);  a5 += __shfl_xor(a5, o, 64);
        a6 += __shfl_xor(a6, o, 64);  a7 += __shfl_xor(a7, o, 64);
    }

    if (g == 0) {
        float4 lo, hi;
        lo.x = a0 + bf2f(xs[0]); lo.y = a1 + bf2f(xs[1]);
        lo.z = a2 + bf2f(xs[2]); lo.w = a3 + bf2f(xs[3]);
        hi.x = a4 + bf2f(xs[4]); hi.y = a5 + bf2f(xs[5]);
        hi.z = a6 + bf2f(xs[6]); hi.w = a7 + bf2f(xs[7]);
        *(float4*)&h[(size_t)n * D + sub * 8]     = lo;
        *(float4*)&h[(size_t)n * D + sub * 8 + 4] = hi;
    }
}

// ---------------------------------------------------------------------------
// MLP: relu(relu(h@W1+b1)@W2+b2). Weights pinned in VGPRs; wave-local LDS
// broadcast; 4 partial accumulators. Writes bf16 x. LAST=1 fuses pool + Wout.
// ---------------------------------------------------------------------------
template <int LAST>
__global__ __launch_bounds__(256, 1) void mlp_kernel(
    const float* __restrict__ hin, u16* __restrict__ xout,
    const float* __restrict__ W1, const float* __restrict__ b1,
    const float* __restrict__ W2, const float* __restrict__ b2,
    const int* __restrict__ batch, const float* __restrict__ Wout,
    float* __restrict__ out, int N, int chunk)
{
    __shared__ __align__(16) float sh[4][D];
    __shared__ __align__(16) float sh2[4][D];

    const int lane = threadIdx.x & 63;
    const int wid  = threadIdx.x >> 6;

    float w1[D], w2[D];
#pragma unroll
    for (int k = 0; k < D; ++k) w1[k] = W1[k * D + lane];
#pragma unroll
    for (int k = 0; k < D; ++k) w2[k] = W2[k * D + lane];
#pragma unroll
    for (int k = 0; k < D; ++k) { asm volatile("" : "+v"(w1[k])); asm volatile("" : "+v"(w2[k])); }
    const float b1l = b1[lane];
    const float b2l = b2[lane];
    const float wo  = LAST ? Wout[lane] : 0.f;

    const int w = (blockIdx.x << 2) + wid;
    int n0 = w * chunk;
    if (n0 >= N) return;
    int n1 = min(n0 + chunk, N);

    float gsum = 0.f;
    int   curg = -1;

    for (int n = n0; n < n1; ++n) {
        float hv = hin[(size_t)n * D + lane];
        sh[wid][lane] = hv;

        float t0 = 0.f, t1 = 0.f, t2 = 0.f, t3 = 0.f;
#pragma unroll
        for (int k = 0; k < D; k += 4) {
            float4 hk = *(const float4*)&sh[wid][k];
            t0 = fmaf(hk.x, w1[k + 0], t0);
            t1 = fmaf(hk.y, w1[k + 1], t1);
            t2 = fmaf(hk.z, w1[k + 2], t2);
            t3 = fmaf(hk.w, w1[k + 3], t3);
        }
        float hid = fmaxf(((t0 + t1) + (t2 + t3)) + b1l, 0.f);
        sh2[wid][lane] = hid;

        float s0 = 0.f, s1 = 0.f, s2 = 0.f, s3 = 0.f;
#pragma unroll
        for (int k = 0; k < D; k += 4) {
            float4 hk = *(const float4*)&sh2[wid][k];
            s0 = fmaf(hk.x, w2[k + 0], s0);
            s1 = fmaf(hk.y, w2[k + 1], s1);
            s2 = fmaf(hk.z, w2[k + 2], s2);
            s3 = fmaf(hk.w, w2[k + 3], s3);
        }
        float r = fmaxf(((s0 + s1) + (s2 + s3)) + b2l, 0.f);

        if (LAST) {
            float s = r * wo;
#pragma unroll
            for (int o = 32; o; o >>= 1) s += __shfl_xor(s, o, 64);
            int gb = batch[n];
            if (gb != curg) {
                if (curg >= 0 && lane == 0) atomicAdd(&out[curg], gsum);
                curg = gb;
                gsum = s;
            } else {
                gsum += s;
            }
        } else {
            xout[(size_t)n * D + lane] = f2bf(r);
        }
    }
    if (LAST && curg >= 0 && lane == 0) atomicAdd(&out[curg], gsum);
}

// ---------------------------------------------------------------------------
extern "C" void kernel_launch(void* const* d_in, const int* in_sizes, int n_in,
                              void* d_out, int out_size, void* d_ws, size_t ws_size,
                              hipStream_t stream) {
    const float* x     = (const float*)d_in[0];
    const int*   ei    = (const int*)d_in[1];
    const float* ea    = (const float*)d_in[2];
    const int*   batch = (const int*)d_in[3];
    const float* W1    = (const float*)d_in[4];
    const float* b1    = (const float*)d_in[5];
    const float* W2    = (const float*)d_in[6];
    const float* b2    = (const float*)d_in[7];
    const float* Wout  = (const float*)d_in[8];
    const float* bout  = (const float*)d_in[9];
    float* out = (float*)d_out;

    const int N = in_sizes[0] / D;   // 100000
    const int E = in_sizes[1] / 2;   // 1200000
    const int G = out_size;          // 128
    const int NB = (N + BSZ - 1) / BSZ;   // 196 buckets

    // ---- workspace layout ----
    char* w = (char*)d_ws;
    u16*   xbfA    = (u16*)w;              w += (size_t)N * D * sizeof(u16);
    u16*   xbfB    = (u16*)w;              w += (size_t)N * D * sizeof(u16);
    float* hbuf    = (float*)w;            w += (size_t)N * D * sizeof(float);
    int*   src_csr = (int*)w;              w += (size_t)E * sizeof(int);
    int*   pos     = (int*)w;              w += (size_t)E * sizeof(int);
    int*   deg     = (int*)w;              w += (size_t)N * sizeof(int);
    int*   off     = (int*)w;              w += (size_t)N * sizeof(int);
    int*   cur     = (int*)w;              w += (size_t)N * sizeof(int);
    int*   bbase   = (int*)w;              w += 256 * sizeof(int);
    int*   bcur    = (int*)w;              w += 256 * sizeof(int);
    int*   bsum    = (int*)w;              w += 128 * sizeof(int);
    int*   boff    = (int*)w;              w += 128 * sizeof(int);
    u16*   stage   = (u16*)w;              // E*D*2 bytes

    const int nScanBlocks = (N + 1023) / 1024;
    const int edgeBlocks  = (E + 255) / 256;
    const int buildBlocks = (E + 15) / 16;
    const int aggBlocks   = (N + 3) / 4;       // one wave per node

    const long long nx4 = (long long)N * D / 4;
    const int convxBlocks = (int)((nx4 + 255) / 256);

    const int mlpWaves  = 4096;
    const int mlpBlocks = mlpWaves / 4;
    const int chunk     = (N + mlpWaves - 1) / mlpWaves;

    out_init_kernel<<<(G + 127) / 128, 128, 0, stream>>>(out, bout, G);

    // ---- CSR build (bucket-append staging) + x0 bf16 convert ----
    hipMemsetAsync(deg, 0, (size_t)N * sizeof(int), stream);
    hipMemsetAsync(cur, 0, (size_t)N * sizeof(int), stream);
    hipMemsetAsync(bcur, 0, 256 * sizeof(int), stream);
    deg_hist_kernel<<<edgeBlocks, 256, 0, stream>>>(ei, deg, E);
    scan1_kernel<<<nScanBlocks, 1024, 0, stream>>>(deg, off, bsum, N);
    scan2_kernel<<<1, 128, 0, stream>>>(bsum, boff, nScanBlocks);
    scan3_kernel<<<(N + 255) / 256, 256, 0, stream>>>(off, boff, N);
    bucket_base_kernel<<<(NB + 127) / 128, 128, 0, stream>>>(off, bbase, N, NB);
    build2_kernel<<<buildBlocks, 256, 0, stream>>>(ea, ei, off, cur, bbase, bcur,
                                                   src_csr, pos, stage, E);
    convx_kernel<<<convxBlocks, 256, 0, stream>>>(x, xbfA, nx4);

    // ---- 3 layers: aggregate -> mlp ----
    u16* xcur = xbfA;
    u16* xnxt = xbfB;
    for (int l = 0; l < 3; ++l) {
        aggregate_kernel<<<aggBlocks, 256, 0, stream>>>(xcur, stage, src_csr, pos,
                                                        off, deg, hbuf, N);
        if (l < 2) {
            mlp_kernel<0><<<mlpBlocks, 256, 0, stream>>>(hbuf, xnxt,
                W1 + l * D * D, b1 + l * D, W2 + l * D * D, b2 + l * D,
                batch, Wout, out, N, chunk);
            u16* t = xcur; xcur = xnxt; xnxt = t;
        } else {
            mlp_kernel<1><<<mlpBlocks, 256, 0, stream>>>(hbuf, nullptr,
                W1 + l * D * D, b1 + l * D, W2 + l * D * D, b2 + l * D,
                batch, Wout, out, N, chunk);
        }
    }
}

// Round 13
// 380.737 us; speedup vs baseline: 5.6065x; 5.6065x over previous
//
#include <hip/hip_runtime.h>
#include <hip/hip_bf16.h>

#define D 64

typedef unsigned short u16;
typedef unsigned long long u64;
typedef __attribute__((ext_vector_type(8))) unsigned short u16x8;
typedef __attribute__((ext_vector_type(8))) short bf16x8;
typedef __attribute__((ext_vector_type(4))) float f32x4;

static __device__ __forceinline__ u16 f2bf(float f) {
    unsigned u = __float_as_uint(f);
    unsigned r = (u + 0x7FFFu + ((u >> 16) & 1u)) >> 16;   // RNE
    return (u16)r;
}
static __device__ __forceinline__ float bf2f(u16 h) {
    return __uint_as_float(((unsigned)h) << 16);
}

// ---------------------------------------------------------------------------
__global__ void out_init_kernel(float* __restrict__ out, const float* __restrict__ bout, int G) {
    int i = blockIdx.x * blockDim.x + threadIdx.x;
    if (i < G) out[i] = bout[0];
}

// ---------------------------------------------------------------------------
// CSR build: histogram -> scan
// ---------------------------------------------------------------------------
__global__ void deg_hist_kernel(const int* __restrict__ ei, int* __restrict__ deg, int E) {
    int e = blockIdx.x * blockDim.x + threadIdx.x;
    if (e < E) atomicAdd(&deg[ei[E + e]], 1);
}

__global__ __launch_bounds__(1024) void scan1_kernel(
    const int* __restrict__ deg, int* __restrict__ off, int* __restrict__ bsum, int N)
{
    __shared__ int sh[1024];
    int t = threadIdx.x;
    int i = blockIdx.x * 1024 + t;
    int v = (i < N) ? deg[i] : 0;
    sh[t] = v;
    __syncthreads();
#pragma unroll
    for (int o = 1; o < 1024; o <<= 1) {
        int u = (t >= o) ? sh[t - o] : 0;
        __syncthreads();
        sh[t] += u;
        __syncthreads();
    }
    if (i < N) off[i] = sh[t] - v;
    if (t == 1023) bsum[blockIdx.x] = sh[t];
}

__global__ __launch_bounds__(128) void scan2_kernel(
    const int* __restrict__ bsum, int* __restrict__ boff, int nb)
{
    __shared__ int sh[128];
    int t = threadIdx.x;
    int v = (t < nb) ? bsum[t] : 0;
    sh[t] = v;
    __syncthreads();
#pragma unroll
    for (int o = 1; o < 128; o <<= 1) {
        int u = (t >= o) ? sh[t - o] : 0;
        __syncthreads();
        sh[t] += u;
        __syncthreads();
    }
    if (t < nb) boff[t] = sh[t] - v;
}

__global__ void scan3_kernel(int* __restrict__ off, const int* __restrict__ boff, int N) {
    int i = blockIdx.x * blockDim.x + threadIdx.x;
    if (i < N) off[i] += boff[i >> 10];
}

// ---------------------------------------------------------------------------
// build: fused scatter + reorder.  Wave handles 4 edges, 16 lanes/edge.
// Sequential fp32 ea read, bf16 row (128B) NT write to CSR slot.
// ---------------------------------------------------------------------------
__global__ __launch_bounds__(256) void build_kernel(
    const float* __restrict__ ea, const int* __restrict__ ei,
    const int* __restrict__ off, int* __restrict__ cur,
    int* __restrict__ src_csr, u16* __restrict__ ea_csr, int E)
{
    const int lane = threadIdx.x & 63;
    const int q = lane & 15, g = lane >> 4;
    const long long wv = (long long)blockIdx.x * 4 + (threadIdx.x >> 6);
    const int e = (int)(wv * 4) + g;

    int p = 0, s = 0;
    if (e < E && q == 0) {
        int d = ei[E + e];
        s = ei[e];
        p = off[d] + atomicAdd(&cur[d], 1);
    }
    p = __shfl(p, lane & 48, 64);        // broadcast group leader's slot
    if (e >= E) return;

    float4 v = *(const float4*)&ea[(size_t)e * D + q * 4];
    u64 pk = (u64)f2bf(v.x) | ((u64)f2bf(v.y) << 16)
           | ((u64)f2bf(v.z) << 32) | ((u64)f2bf(v.w) << 48);
    __builtin_nontemporal_store(pk, (u64*)&ea_csr[(size_t)p * D + q * 4]);
    if (q == 0) src_csr[p] = s;
}

// ---------------------------------------------------------------------------
// convx: fp32 node features -> bf16 (identity order, fully sequential)
// ---------------------------------------------------------------------------
__global__ __launch_bounds__(256) void convx_kernel(
    const float* __restrict__ xf, u16* __restrict__ xb, long long n4)
{
    long long i = (long long)blockIdx.x * blockDim.x + threadIdx.x;
    if (i >= n4) return;
    float4 v = ((const float4*)xf)[i];
    ushort4 o;
    o.x = f2bf(v.x); o.y = f2bf(v.y); o.z = f2bf(v.z); o.w = f2bf(v.w);
    ((ushort4*)xb)[i] = o;
}

// ---------------------------------------------------------------------------
// aggregate: wave per node, 8 lanes/edge, 8 edges per chunk, 2-deep pipeline.
// h written in bf16 (MFMA A-operand format is row-major bf16).
// ---------------------------------------------------------------------------
__global__ __launch_bounds__(256) void aggregate_kernel(
    const u16* __restrict__ xbf, const u16* __restrict__ ea_csr,
    const int* __restrict__ src_csr, const int* __restrict__ off,
    const int* __restrict__ deg, u16* __restrict__ hbf, int N)
{
    const int lane = threadIdx.x & 63;
    const int sub  = lane & 7;        // dim octet
    const int g    = lane >> 3;       // edge slot 0..7
    const int n = (blockIdx.x << 2) + (threadIdx.x >> 6);
    if (n >= N) return;

    const int p0 = off[n];
    const int dg = deg[n];

    u16x8 xs;                          // self row (consumed at the end)
    if (g == 0) xs = *(const u16x8*)&xbf[(size_t)n * D + sub * 8];

    float a0=0.f,a1=0.f,a2=0.f,a3=0.f,a4=0.f,a5=0.f,a6=0.f,a7=0.f;

    if (dg > 0) {
        const int srcAll = src_csr[p0 + min(lane, dg - 1)];  // one coalesced load
        const int nct = (dg + 7) >> 3;

        // ---- issue chunk 0 ----
        int e0 = min(g, dg - 1);
        int sv = __shfl(srcAll, e0, 64);
        int s0 = sv;
        u16x8 evA = *(const u16x8*)&ea_csr[(size_t)(p0 + e0) * D + sub * 8];
        u16x8 xvA = *(const u16x8*)&xbf[(size_t)s0 * D + sub * 8];
        float mA = (g < dg) ? 1.f : 0.f;

        for (int c = 1; c < nct; ++c) {
            int e1 = min(c * 8 + g, dg - 1);
            int sv1 = __shfl(srcAll, e1 & 63, 64);
            int s1 = (e1 < 64) ? sv1 : src_csr[p0 + e1];
            u16x8 evB = *(const u16x8*)&ea_csr[(size_t)(p0 + e1) * D + sub * 8];
            u16x8 xvB = *(const u16x8*)&xbf[(size_t)s1 * D + sub * 8];
            float mB = (c * 8 + g < dg) ? 1.f : 0.f;

            a0 = fmaf(mA, fmaxf(bf2f(xvA[0]) + bf2f(evA[0]), 0.f), a0);
            a1 = fmaf(mA, fmaxf(bf2f(xvA[1]) + bf2f(evA[1]), 0.f), a1);
            a2 = fmaf(mA, fmaxf(bf2f(xvA[2]) + bf2f(evA[2]), 0.f), a2);
            a3 = fmaf(mA, fmaxf(bf2f(xvA[3]) + bf2f(evA[3]), 0.f), a3);
            a4 = fmaf(mA, fmaxf(bf2f(xvA[4]) + bf2f(evA[4]), 0.f), a4);
            a5 = fmaf(mA, fmaxf(bf2f(xvA[5]) + bf2f(evA[5]), 0.f), a5);
            a6 = fmaf(mA, fmaxf(bf2f(xvA[6]) + bf2f(evA[6]), 0.f), a6);
            a7 = fmaf(mA, fmaxf(bf2f(xvA[7]) + bf2f(evA[7]), 0.f), a7);

            xvA = xvB; evA = evB; mA = mB;
        }
        a0 = fmaf(mA, fmaxf(bf2f(xvA[0]) + bf2f(evA[0]), 0.f), a0);
        a1 = fmaf(mA, fmaxf(bf2f(xvA[1]) + bf2f(evA[1]), 0.f), a1);
        a2 = fmaf(mA, fmaxf(bf2f(xvA[2]) + bf2f(evA[2]), 0.f), a2);
        a3 = fmaf(mA, fmaxf(bf2f(xvA[3]) + bf2f(evA[3]), 0.f), a3);
        a4 = fmaf(mA, fmaxf(bf2f(xvA[4]) + bf2f(evA[4]), 0.f), a4);
        a5 = fmaf(mA, fmaxf(bf2f(xvA[5]) + bf2f(evA[5]), 0.f), a5);
        a6 = fmaf(mA, fmaxf(bf2f(xvA[6]) + bf2f(evA[6]), 0.f), a6);
        a7 = fmaf(mA, fmaxf(bf2f(xvA[7]) + bf2f(evA[7]), 0.f), a7);
    }

    // reduce across the 8 edge-groups
#pragma unroll
    for (int o = 8; o < 64; o <<= 1) {
        a0 += __shfl_xor(a0, o, 64);  a1 += __shfl_xor(a1, o, 64);
        a2 += __shfl_xor(a2, o, 64);  a3 += __shfl_xor(a3, o, 64);
        a4 += __shfl_xor(a4, o, 64);  a5 += __shfl_xor(a5, o, 64);
        a6 += __shfl_xor(a6, o, 64);  a7 += __shfl_xor(a7, o, 64);
    }

    if (g == 0) {
        u16x8 ho;
        ho[0] = f2bf(a0 + bf2f(xs[0]));
        ho[1] = f2bf(a1 + bf2f(xs[1]));
        ho[2] = f2bf(a2 + bf2f(xs[2]));
        ho[3] = f2bf(a3 + bf2f(xs[3]));
        ho[4] = f2bf(a4 + bf2f(xs[4]));
        ho[5] = f2bf(a5 + bf2f(xs[5]));
        ho[6] = f2bf(a6 + bf2f(xs[6]));
        ho[7] = f2bf(a7 + bf2f(xs[7]));
        *(u16x8*)&hbf[(size_t)n * D + sub * 8] = ho;
    }
}

// ---------------------------------------------------------------------------
// MFMA MLP: X = relu(relu(H@W1+b1)@W2+b2), H bf16 row-major.
// Block = 4 waves; M-tile 64 rows (16/wave). W1,W2 held as B-fragments in
// VGPRs (loaded once per block, amortized via grid-stride). Hidden
// redistributed through padded LDS (stride 72 -> 2-way conflicts only).
// Layouts (guide, m89/m91): A row=l&15,k=(l>>4)*8+j; B k=(l>>4)*8+j,col=l&15;
// C col=l&15,row=(l>>4)*4+reg.
// LAST=1: fused global_add_pool via LDS 128-bin accumulation + Wout.
// ---------------------------------------------------------------------------
template <int LAST>
__global__ __launch_bounds__(256) void mlp_mfma_kernel(
    const u16* __restrict__ hbf, u16* __restrict__ xout,
    const float* __restrict__ W1, const float* __restrict__ b1,
    const float* __restrict__ W2, const float* __restrict__ b2,
    const int* __restrict__ batch, const float* __restrict__ Wout,
    float* __restrict__ out, int N, int ntiles)
{
    __shared__ __align__(16) u16 lds_h[4][16][72];   // padded: 2-way banks only
    __shared__ float pool[128];

    const int lane = threadIdx.x & 63;
    const int wid  = threadIdx.x >> 6;
    const int lr   = lane & 15;      // A-row / B-col / C-col
    const int lg   = lane >> 4;      // k-group / C row-group

    if (LAST) {
        if (threadIdx.x < 128) pool[threadIdx.x] = 0.f;
        __syncthreads();
    }

    // ---- weight B-fragments: full W1,W2 per wave (64 VGPR) ----
    bf16x8 w1f[4][2], w2f[4][2];
#pragma unroll
    for (int nt = 0; nt < 4; ++nt)
#pragma unroll
      for (int ks = 0; ks < 2; ++ks) {
        bf16x8 f1, f2;
#pragma unroll
        for (int j = 0; j < 8; ++j) {
            int k = ks * 32 + lg * 8 + j;
            int c = nt * 16 + lr;
            f1[j] = (short)f2bf(W1[k * D + c]);
            f2[j] = (short)f2bf(W2[k * D + c]);
        }
        w1f[nt][ks] = f1; w2f[nt][ks] = f2;
      }
    float b1v[4], b2v[4], wov[4];
#pragma unroll
    for (int nt = 0; nt < 4; ++nt) {
        b1v[nt] = b1[nt * 16 + lr];
        b2v[nt] = b2[nt * 16 + lr];
        wov[nt] = LAST ? Wout[nt * 16 + lr] : 0.f;
    }

    for (int t = blockIdx.x; t < ntiles; t += gridDim.x) {
        const int m0 = t * 64 + wid * 16;
        if (m0 < N) {
            // ---- A1 fragments from global h ----
            const int ra = min(m0 + lr, N - 1);
            bf16x8 a0 = *(const bf16x8*)&hbf[(size_t)ra * D + lg * 8];
            bf16x8 a1 = *(const bf16x8*)&hbf[(size_t)ra * D + 32 + lg * 8];

            // ---- GEMM1 ----
            f32x4 c1[4];
#pragma unroll
            for (int nt = 0; nt < 4; ++nt) {
                f32x4 z = {0.f, 0.f, 0.f, 0.f};
                z = __builtin_amdgcn_mfma_f32_16x16x32_bf16(a0, w1f[nt][0], z, 0, 0, 0);
                z = __builtin_amdgcn_mfma_f32_16x16x32_bf16(a1, w1f[nt][1], z, 0, 0, 0);
                c1[nt] = z;
            }
            // bias + relu -> LDS (wave-local region, wave-synchronous)
#pragma unroll
            for (int nt = 0; nt < 4; ++nt)
#pragma unroll
              for (int j = 0; j < 4; ++j) {
                float v = fmaxf(c1[nt][j] + b1v[nt], 0.f);
                lds_h[wid][lg * 4 + j][nt * 16 + lr] = f2bf(v);
              }

            // ---- A2 fragments from LDS ----
            bf16x8 h0 = *(const bf16x8*)&lds_h[wid][lr][lg * 8];
            bf16x8 h1 = *(const bf16x8*)&lds_h[wid][lr][32 + lg * 8];

            // ---- GEMM2 ----
            f32x4 c2[4];
#pragma unroll
            for (int nt = 0; nt < 4; ++nt) {
                f32x4 z = {0.f, 0.f, 0.f, 0.f};
                z = __builtin_amdgcn_mfma_f32_16x16x32_bf16(h0, w2f[nt][0], z, 0, 0, 0);
                z = __builtin_amdgcn_mfma_f32_16x16x32_bf16(h1, w2f[nt][1], z, 0, 0, 0);
                c2[nt] = z;
            }

            if (!LAST) {
#pragma unroll
                for (int nt = 0; nt < 4; ++nt)
#pragma unroll
                  for (int j = 0; j < 4; ++j) {
                    int gr = m0 + lg * 4 + j;
                    if (gr < N) {
                        float v = fmaxf(c2[nt][j] + b2v[nt], 0.f);
                        xout[(size_t)gr * D + nt * 16 + lr] = f2bf(v);
                    }
                  }
            } else {
                float s0 = 0.f, s1 = 0.f, s2 = 0.f, s3 = 0.f;
#pragma unroll
                for (int nt = 0; nt < 4; ++nt) {
                    s0 = fmaf(fmaxf(c2[nt][0] + b2v[nt], 0.f), wov[nt], s0);
                    s1 = fmaf(fmaxf(c2[nt][1] + b2v[nt], 0.f), wov[nt], s1);
                    s2 = fmaf(fmaxf(c2[nt][2] + b2v[nt], 0.f), wov[nt], s2);
                    s3 = fmaf(fmaxf(c2[nt][3] + b2v[nt], 0.f), wov[nt], s3);
                }
#pragma unroll
                for (int o = 1; o < 16; o <<= 1) {
                    s0 += __shfl_xor(s0, o, 64);
                    s1 += __shfl_xor(s1, o, 64);
                    s2 += __shfl_xor(s2, o, 64);
                    s3 += __shfl_xor(s3, o, 64);
                }
                if (lr == 0) {
                    int gr = m0 + lg * 4;
                    if (gr + 0 < N) atomicAdd(&pool[batch[gr + 0]], s0);
                    if (gr + 1 < N) atomicAdd(&pool[batch[gr + 1]], s1);
                    if (gr + 2 < N) atomicAdd(&pool[batch[gr + 2]], s2);
                    if (gr + 3 < N) atomicAdd(&pool[batch[gr + 3]], s3);
                }
            }
        }
    }

    if (LAST) {
        __syncthreads();
        if (threadIdx.x < 128) {
            float v = pool[threadIdx.x];
            if (v != 0.f) atomicAdd(&out[threadIdx.x], v);
        }
    }
}

// ---------------------------------------------------------------------------
extern "C" void kernel_launch(void* const* d_in, const int* in_sizes, int n_in,
                              void* d_out, int out_size, void* d_ws, size_t ws_size,
                              hipStream_t stream) {
    const float* x     = (const float*)d_in[0];
    const int*   ei    = (const int*)d_in[1];
    const float* ea    = (const float*)d_in[2];
    const int*   batch = (const int*)d_in[3];
    const float* W1    = (const float*)d_in[4];
    const float* b1    = (const float*)d_in[5];
    const float* W2    = (const float*)d_in[6];
    const float* b2    = (const float*)d_in[7];
    const float* Wout  = (const float*)d_in[8];
    const float* bout  = (const float*)d_in[9];
    float* out = (float*)d_out;

    const int N = in_sizes[0] / D;   // 100000
    const int E = in_sizes[1] / 2;   // 1200000
    const int G = out_size;          // 128

    // ---- workspace layout ----
    char* w = (char*)d_ws;
    u16*   xbfA    = (u16*)w;              w += (size_t)N * D * sizeof(u16);
    u16*   xbfB    = (u16*)w;              w += (size_t)N * D * sizeof(u16);
    u16*   hbf     = (u16*)w;              w += (size_t)N * D * sizeof(u16);
    int*   src_csr = (int*)w;              w += (size_t)E * sizeof(int);
    int*   deg     = (int*)w;              w += (size_t)N * sizeof(int);
    int*   off     = (int*)w;              w += (size_t)N * sizeof(int);
    int*   cur     = (int*)w;              w += (size_t)N * sizeof(int);
    int*   bsum    = (int*)w;              w += 128 * sizeof(int);
    int*   boff    = (int*)w;              w += 128 * sizeof(int);
    u16*   ea_csr  = (u16*)w;              // E*D*2 bytes

    const int nScanBlocks = (N + 1023) / 1024;
    const int edgeBlocks  = (E + 255) / 256;
    const int buildBlocks = (E + 15) / 16;
    const int aggBlocks   = (N + 3) / 4;       // one wave per node

    const long long nx4 = (long long)N * D / 4;
    const int convxBlocks = (int)((nx4 + 255) / 256);

    const int ntiles    = (N + 63) / 64;       // 1563
    const int mlpBlocks = 782;                 // ~2 tiles/block, weights amortized

    out_init_kernel<<<(G + 127) / 128, 128, 0, stream>>>(out, bout, G);

    // ---- CSR build + bf16 edge reorder + x0 bf16 convert ----
    hipMemsetAsync(deg, 0, (size_t)N * sizeof(int), stream);
    hipMemsetAsync(cur, 0, (size_t)N * sizeof(int), stream);
    deg_hist_kernel<<<edgeBlocks, 256, 0, stream>>>(ei, deg, E);
    scan1_kernel<<<nScanBlocks, 1024, 0, stream>>>(deg, off, bsum, N);
    scan2_kernel<<<1, 128, 0, stream>>>(bsum, boff, nScanBlocks);
    scan3_kernel<<<(N + 255) / 256, 256, 0, stream>>>(off, boff, N);
    build_kernel<<<buildBlocks, 256, 0, stream>>>(ea, ei, off, cur, src_csr, ea_csr, E);
    convx_kernel<<<convxBlocks, 256, 0, stream>>>(x, xbfA, nx4);

    // ---- 3 layers: aggregate -> MFMA mlp ----
    u16* xcur = xbfA;
    u16* xnxt = xbfB;
    for (int l = 0; l < 3; ++l) {
        aggregate_kernel<<<aggBlocks, 256, 0, stream>>>(xcur, ea_csr, src_csr,
                                                        off, deg, hbf, N);
        if (l < 2) {
            mlp_mfma_kernel<0><<<mlpBlocks, 256, 0, stream>>>(hbf, xnxt,
                W1 + l * D * D, b1 + l * D, W2 + l * D * D, b2 + l * D,
                batch, Wout, out, N, ntiles);
            u16* t = xcur; xcur = xnxt; xnxt = t;
        } else {
            mlp_mfma_kernel<1><<<mlpBlocks, 256, 0, stream>>>(hbf, nullptr,
                W1 + l * D * D, b1 + l * D, W2 + l * D * D, b2 + l * D,
                batch, Wout, out, N, ntiles);
        }
    }
}